// Round 8
// baseline (466.993 us; speedup 1.0000x reference)
//
#include <hip/hip_runtime.h>
#include <hip/hip_cooperative_groups.h>

namespace cg = cooperative_groups;

#define INDIM  256
#define HIDDEN 128
#define OUTD   64

typedef short  bf16x8 __attribute__((ext_vector_type(8)));
typedef float  f32x4  __attribute__((ext_vector_type(4)));
typedef float  f32x2  __attribute__((ext_vector_type(2)));
typedef ushort u16x8  __attribute__((ext_vector_type(8)));

__device__ inline float bf2f(ushort h) {
    union { unsigned u; float f; } v; v.u = ((unsigned)h) << 16; return v.f;
}
__device__ inline ushort f2bf(float f) {
    union { float f; unsigned u; } v; v.f = f;
    unsigned u = v.u;
    unsigned r = (u + 0x7FFFu + ((u >> 16) & 1u)) >> 16;  // RNE
    return (ushort)r;
}
__device__ inline f32x2 fp8x2_dec(int packed) {
    return __builtin_amdgcn_cvt_pk_f32_fp8(packed, false);
}
__device__ inline unsigned char fp8_enc(float v) {
    int pk = __builtin_amdgcn_cvt_pk_fp8_f32(v, v, 0, false);
    return (unsigned char)(pk & 0xFF);
}

__device__ inline float wsum(float v) {
    #pragma unroll
    for (int m = 32; m >= 1; m >>= 1) v += __shfl_xor(v, m);
    return v;
}
__device__ inline float wmax(float v) {
    #pragma unroll
    for (int m = 32; m >= 1; m >>= 1) v = fmaxf(v, __shfl_xor(v, m));
    return v;
}

// ======================= shared GEMM tile body (512 threads) =======================
// A: [M][K] (fp32 if AFP32 else bf16) ; BT: [BN][K] bf16 ; C: [M][BN] fp8 (raw, unscaled)
template<int BM, int BN, int WM, int WN, bool AFP32>
__device__ void gemm_tile(char* pool, int bi, const void* Ap, const ushort* BT,
                          unsigned char* C, int M, int K) {
    constexpr int BK  = 64;
    constexpr int FM  = WM / 16, FN = WN / 16;
    constexpr int NWN = BN / WN;
    constexpr int TH  = (BM / WM) * NWN * 64;
    static_assert(TH == 512, "tile geometry must use 512 threads");
    char* Ab = pool;
    char* Bb = pool + BM * BK * 2;
    int tid  = threadIdx.x;
    int lane = tid & 63, w = tid >> 6;
    int wm = w / NWN, wn = w % NWN;
    long m0 = (long)bi * BM;
    f32x4 acc[FM][FN] = {};

    for (int kt = 0; kt < K; kt += BK) {
        #pragma unroll
        for (int c = tid; c < BM * BK / 8; c += TH) {
            int row = c / (BK / 8);
            int kc  = (c % (BK / 8)) * 8;
            int off = ((row * BK + kc) * 2) ^ ((row & 7) << 4);
            u16x8 pk = {0, 0, 0, 0, 0, 0, 0, 0};
            long g = m0 + row;
            if (g < M) {
                if (AFP32) {
                    const float* A = (const float*)Ap;
                    float4 v0 = *(const float4*)(A + g * K + kt + kc);
                    float4 v1 = *(const float4*)(A + g * K + kt + kc + 4);
                    pk[0] = f2bf(v0.x); pk[1] = f2bf(v0.y); pk[2] = f2bf(v0.z); pk[3] = f2bf(v0.w);
                    pk[4] = f2bf(v1.x); pk[5] = f2bf(v1.y); pk[6] = f2bf(v1.z); pk[7] = f2bf(v1.w);
                } else {
                    const ushort* A = (const ushort*)Ap;
                    pk = *(const u16x8*)(A + g * K + kt + kc);
                }
            }
            *(u16x8*)(Ab + off) = pk;
        }
        #pragma unroll
        for (int c = tid; c < BN * BK / 8; c += TH) {
            int nn = c / (BK / 8);
            int kc = (c % (BK / 8)) * 8;
            int off = ((nn * BK + kc) * 2) ^ ((nn & 7) << 4);
            *(u16x8*)(Bb + off) = *(const u16x8*)(BT + (long)nn * K + kt + kc);
        }
        __syncthreads();
        #pragma unroll
        for (int kk = 0; kk < BK / 32; ++kk) {
            int kb = kk * 32 + (lane >> 4) * 8;
            bf16x8 af[FM], bfv[FN];
            #pragma unroll
            for (int i = 0; i < FM; ++i) {
                int row = wm * WM + i * 16 + (lane & 15);
                af[i] = *(const bf16x8*)(Ab + (((row * BK + kb) * 2) ^ ((row & 7) << 4)));
            }
            #pragma unroll
            for (int j = 0; j < FN; ++j) {
                int nn = wn * WN + j * 16 + (lane & 15);
                bfv[j] = *(const bf16x8*)(Bb + (((nn * BK + kb) * 2) ^ ((nn & 7) << 4)));
            }
            #pragma unroll
            for (int i = 0; i < FM; ++i)
                #pragma unroll
                for (int j = 0; j < FN; ++j)
                    acc[i][j] = __builtin_amdgcn_mfma_f32_16x16x32_bf16(af[i], bfv[j], acc[i][j], 0, 0, 0);
        }
        __syncthreads();
    }

    #pragma unroll
    for (int i = 0; i < FM; ++i) {
        #pragma unroll
        for (int q = 0; q < 4; ++q) {
            long row = m0 + wm * WM + i * 16 + (lane >> 4) * 4 + q;
            if (row < M) {
                #pragma unroll
                for (int j = 0; j < FN; ++j) {
                    int col = wn * WN + j * 16 + (lane & 15);
                    C[row * BN + col] = fp8_enc(acc[i][j][q]);
                }
            }
        }
    }
}

// ======================= mega kernel (cooperative) =======================
struct MegaP {
    const float* x; const int* srcv; const int* dstv;
    const float* W1; const float* b1; const float* W2; const float* b2;
    const float* We; const float* be; const float* Wg; const float* bg; const float* rw;
    float* out;
    int n, E, nbkt;
    int* bkt_cnt; int* bkt_off; int* bkt_cur; int* row_start; float* dinv;
    unsigned* binned; int* csr_src; int* tile_ctr;
    unsigned char* g1; ushort* h1; ushort* W1T; ushort* W2T; unsigned char* g2;
};

__device__ void steal_gemm1(char* pool, const MegaP& p) {
    __shared__ int ts;
    int nt = (p.n + 63) / 64;
    while (true) {
        if (threadIdx.x == 0) ts = atomicAdd(p.tile_ctr, 1);
        __syncthreads();
        int t = ts;
        if (t >= nt) break;
        gemm_tile<64, 128, 32, 32, true>(pool, t, p.x, p.W1T, p.g1, p.n, INDIM);
    }
}

__global__ void __launch_bounds__(512) mega(MegaP p) {
    cg::grid_group grid = cg::this_grid();
    __shared__ alignas(16) char pool[24576];
    const int tid = threadIdx.x;
    const int bid = blockIdx.x;
    const int nb  = gridDim.x;
    const int gsz = nb * 512;
    const int gt  = bid * 512 + tid;
    const int wv = tid >> 6, lane = tid & 63;

    // ---- P0: zero counters; W1->W1T, W2->W2T (bf16, transposed) ----
    if (gt < 256) p.bkt_cnt[gt] = 0;
    if (gt == 0) *p.tile_ctr = 0;
    for (int i = gt; i < INDIM * HIDDEN; i += gsz) {
        int k = i / HIDDEN, c = i % HIDDEN;
        p.W1T[c * INDIM + k] = f2bf(p.W1[i]);
    }
    for (int i = gt; i < HIDDEN * OUTD; i += gsz) {
        int k = i / OUTD, c = i % OUTD;
        p.W2T[c * HIDDEN + k] = f2bf(p.W2[i]);
    }
    grid.sync();

    // ---- P1: bucket histogram ----
    {
        int* h = (int*)pool;
        if (tid < 256) h[tid] = 0;
        __syncthreads();
        for (int e = gt; e < p.E; e += gsz) atomicAdd(&h[p.dstv[e] >> 8], 1);
        __syncthreads();
        if (tid < 256 && h[tid]) atomicAdd(&p.bkt_cnt[tid], h[tid]);
    }
    grid.sync();

    // ---- P2: bucket scan (block 0) + steal gemm1 tiles ----
    if (bid == 0) {
        int* s = (int*)pool;
        int v = 0;
        if (tid < 256) { v = (tid < p.nbkt) ? p.bkt_cnt[tid] : 0; s[tid] = v; }
        __syncthreads();
        for (int off = 1; off < 256; off <<= 1) {
            int t = 0;
            if (tid < 256 && tid >= off) t = s[tid - off];
            __syncthreads();
            if (tid < 256) s[tid] += t;
            __syncthreads();
        }
        if (tid < p.nbkt) {
            int e0 = s[tid] - v;
            p.bkt_off[tid] = e0;
            p.bkt_cur[tid] = e0;
        }
        if (tid == 0) p.row_start[p.n] = p.E;
        __syncthreads();
    }
    steal_gemm1(pool, p);
    grid.sync();

    // ---- P3: scatter packed edges into bucket regions + steal gemm1 ----
    {
        int* h  = (int*)pool;
        int* gb = ((int*)pool) + 256;
        int nch = (p.E + 8191) / 8192;
        for (int ch = bid; ch < nch; ch += nb) {
            if (tid < 256) h[tid] = 0;
            __syncthreads();
            int base = ch * 8192;
            int cnt = min(8192, p.E - base);
            for (int i = tid; i < cnt; i += 512) atomicAdd(&h[p.dstv[base + i] >> 8], 1);
            __syncthreads();
            if (tid < 256) {
                int c = h[tid];
                if (c) gb[tid] = atomicAdd(&p.bkt_cur[tid], c);
                h[tid] = 0;
            }
            __syncthreads();
            for (int i = tid; i < cnt; i += 512) {
                int e = base + i;
                int d = p.dstv[e];
                int b = d >> 8;
                int r = atomicAdd(&h[b], 1);
                p.binned[gb[b] + r] = ((unsigned)(d & 255) << 16) | (unsigned)p.srcv[e];
            }
            __syncthreads();
        }
    }
    steal_gemm1(pool, p);
    grid.sync();

    // ---- P4: per-bucket build (row_start, dinv, csr_src) + drain gemm1 ----
    {
        int* ldeg = (int*)pool;
        int* loff = ((int*)pool) + 256;
        for (int b = bid; b < p.nbkt; b += nb) {
            int base = p.bkt_off[b], cnt = p.bkt_cnt[b];
            if (tid < 256) ldeg[tid] = 0;
            __syncthreads();
            for (int i = tid; i < cnt; i += 512)
                atomicAdd(&ldeg[p.binned[base + i] >> 16], 1);
            __syncthreads();
            int v = 0;
            if (tid < 256) { v = ldeg[tid]; loff[tid] = v; }
            __syncthreads();
            for (int off = 1; off < 256; off <<= 1) {
                int t = 0;
                if (tid < 256 && tid >= off) t = loff[tid - off];
                __syncthreads();
                if (tid < 256) loff[tid] += t;
                __syncthreads();
            }
            if (tid < 256) {
                int excl = loff[tid] - v;
                int node = b * 256 + tid;
                if (node < p.n) {
                    p.row_start[node] = base + excl;
                    p.dinv[node] = rsqrtf((float)(v + 1));
                }
                loff[tid] = excl;
            }
            __syncthreads();
            for (int i = tid; i < cnt; i += 512) {
                unsigned pk = p.binned[base + i];
                int pos = atomicAdd(&loff[pk >> 16], 1);
                p.csr_src[base + pos] = (int)(pk & 0xFFFFu);
            }
            __syncthreads();
        }
    }
    steal_gemm1(pool, p);
    grid.sync();

    // ---- P5: agg1 (edge-weighted by dinv[src]) + bias + relu -> bf16 h1 ----
    {
        int fo = lane * 2;
        for (int node = bid * 8 + wv; node < p.n; node += nb * 8) {
            float dn = p.dinv[node];
            ushort sv = *(const ushort*)&p.g1[(long)node * HIDDEN + fo];
            f32x2 sd = fp8x2_dec((int)sv);
            float a0 = dn * sd[0], a1 = dn * sd[1];
            int s = p.row_start[node], e = p.row_start[node + 1];
            int k = s;
            for (; k + 3 < e; k += 4) {
                int s0 = p.csr_src[k], s1 = p.csr_src[k + 1];
                int s2 = p.csr_src[k + 2], s3 = p.csr_src[k + 3];
                ushort u0 = *(const ushort*)&p.g1[(long)s0 * HIDDEN + fo];
                ushort u1 = *(const ushort*)&p.g1[(long)s1 * HIDDEN + fo];
                ushort u2 = *(const ushort*)&p.g1[(long)s2 * HIDDEN + fo];
                ushort u3 = *(const ushort*)&p.g1[(long)s3 * HIDDEN + fo];
                float w0 = p.dinv[s0], w1 = p.dinv[s1], w2 = p.dinv[s2], w3 = p.dinv[s3];
                f32x2 d0 = fp8x2_dec((int)u0), d1 = fp8x2_dec((int)u1);
                f32x2 d2 = fp8x2_dec((int)u2), d3 = fp8x2_dec((int)u3);
                a0 += w0 * d0[0] + w1 * d1[0] + w2 * d2[0] + w3 * d3[0];
                a1 += w0 * d0[1] + w1 * d1[1] + w2 * d2[1] + w3 * d3[1];
            }
            for (; k < e; ++k) {
                int s0 = p.csr_src[k];
                ushort u0 = *(const ushort*)&p.g1[(long)s0 * HIDDEN + fo];
                f32x2 d0 = fp8x2_dec((int)u0);
                float w0 = p.dinv[s0];
                a0 += w0 * d0[0];
                a1 += w0 * d0[1];
            }
            float2 bb = *(const float2*)&p.b1[fo];
            ushort2 r;
            r.x = f2bf(fmaxf(dn * a0 + bb.x, 0.f));
            r.y = f2bf(fmaxf(dn * a1 + bb.y, 0.f));
            *(ushort2*)&p.h1[(long)node * HIDDEN + fo] = r;
        }
    }
    grid.sync();

    // ---- P6: gemm2 (h1 @ W2 -> fp8 g2, raw) ----
    {
        int nt2 = (p.n + 63) / 64;
        for (int t = bid; t < nt2; t += nb)
            gemm_tile<64, 64, 32, 16, false>(pool, t, p.h1, p.W2T, p.g2, p.n, HIDDEN);
    }
    grid.sync();

    // ---- P7: agg2 + rule/gate + log_softmax ----
    {
        for (int node = bid * 8 + wv; node < p.n; node += nb * 8) {
            float dn = p.dinv[node];
            float acc = dn * fp8x2_dec((int)p.g2[(long)node * OUTD + lane])[0];
            int s = p.row_start[node], e = p.row_start[node + 1];
            int k = s;
            for (; k + 3 < e; k += 4) {
                int s0 = p.csr_src[k], s1 = p.csr_src[k + 1];
                int s2 = p.csr_src[k + 2], s3 = p.csr_src[k + 3];
                float v0 = fp8x2_dec((int)p.g2[(long)s0 * OUTD + lane])[0];
                float v1 = fp8x2_dec((int)p.g2[(long)s1 * OUTD + lane])[0];
                float v2 = fp8x2_dec((int)p.g2[(long)s2 * OUTD + lane])[0];
                float v3 = fp8x2_dec((int)p.g2[(long)s3 * OUTD + lane])[0];
                acc += p.dinv[s0] * v0 + p.dinv[s1] * v1 + p.dinv[s2] * v2 + p.dinv[s3] * v3;
            }
            for (; k < e; ++k) {
                int s0 = p.csr_src[k];
                acc += p.dinv[s0] * fp8x2_dec((int)p.g2[(long)s0 * OUTD + lane])[0];
            }
            float h2 = dn * acc + p.b2[lane];
            float r0 = wsum(h2 * p.We[lane * 3 + 0]) + p.be[0];
            float r1 = wsum(h2 * p.We[lane * 3 + 1]) + p.be[1];
            float r2 = wsum(h2 * p.We[lane * 3 + 2]) + p.be[2];
            float z = r0 * p.Wg[0] + r1 * p.Wg[1] + r2 * p.Wg[2] + p.bg[0];
            float gate = 1.f / (1.f + expf(-z));
            float h = h2 + gate * p.rw[0];
            float m = wmax(h);
            float sum = wsum(expf(h - m));
            p.out[(long)node * OUTD + lane] = h - m - logf(sum);
        }
    }
}

// ======================= fallback path (round-7 kernels) =======================

__global__ void bin_count(const int* __restrict__ dst, int* __restrict__ bkt_cnt, int E) {
    __shared__ int h[256];
    int tid = threadIdx.x;
    h[tid] = 0;
    __syncthreads();
    int base = blockIdx.x * 2048;
    int cnt = min(2048, E - base);
    for (int i = tid; i < cnt; i += 256) atomicAdd(&h[dst[base + i] >> 8], 1);
    __syncthreads();
    if (h[tid]) atomicAdd(&bkt_cnt[tid], h[tid]);
}

__global__ void bkt_scan(const int* __restrict__ bkt_cnt, int* __restrict__ bkt_off,
                         int* __restrict__ bkt_cur, int* __restrict__ row_start,
                         int n, int E, int nbkt) {
    __shared__ int s[256];
    int tid = threadIdx.x;
    int v = (tid < nbkt) ? bkt_cnt[tid] : 0;
    s[tid] = v;
    __syncthreads();
    for (int off = 1; off < 256; off <<= 1) {
        int t = (tid >= off) ? s[tid - off] : 0;
        __syncthreads();
        s[tid] += t;
        __syncthreads();
    }
    if (tid < nbkt) {
        int e = s[tid] - v;
        bkt_off[tid] = e;
        bkt_cur[tid] = e;
    }
    if (tid == 0) row_start[n] = E;
}

__global__ void bin_scatter(const int* __restrict__ src, const int* __restrict__ dst,
                            int* __restrict__ bkt_cur, unsigned* __restrict__ binned, int E) {
    __shared__ int h[256];
    __shared__ int gb[256];
    int tid = threadIdx.x;
    h[tid] = 0;
    __syncthreads();
    int base = blockIdx.x * 8192;
    int cnt = min(8192, E - base);
    for (int i = tid; i < cnt; i += 256) atomicAdd(&h[dst[base + i] >> 8], 1);
    __syncthreads();
    int myc = h[tid];
    if (myc) gb[tid] = atomicAdd(&bkt_cur[tid], myc);
    h[tid] = 0;
    __syncthreads();
    for (int i = tid; i < cnt; i += 256) {
        int e = base + i;
        int d = dst[e];
        int b = d >> 8;
        int r = atomicAdd(&h[b], 1);
        binned[gb[b] + r] = ((unsigned)(d & 255) << 16) | (unsigned)src[e];
    }
}

__global__ void bkt_build(const unsigned* __restrict__ binned, const int* __restrict__ bkt_off,
                          const int* __restrict__ bkt_cnt, int* __restrict__ row_start,
                          float* __restrict__ dinv, int* __restrict__ csr_src, int n) {
    __shared__ int ldeg[256];
    __shared__ int loff[256];
    int b = blockIdx.x, tid = threadIdx.x;
    int base = bkt_off[b], cnt = bkt_cnt[b];
    ldeg[tid] = 0;
    __syncthreads();
    for (int i = tid; i < cnt; i += 256) atomicAdd(&ldeg[binned[base + i] >> 16], 1);
    __syncthreads();
    int v = ldeg[tid];
    loff[tid] = v;
    __syncthreads();
    for (int off = 1; off < 256; off <<= 1) {
        int t = (tid >= off) ? loff[tid - off] : 0;
        __syncthreads();
        loff[tid] += t;
        __syncthreads();
    }
    int excl = loff[tid] - v;
    int node = b * 256 + tid;
    if (node < n) {
        row_start[node] = base + excl;
        dinv[node] = rsqrtf((float)(v + 1));
    }
    __syncthreads();
    loff[tid] = excl;
    __syncthreads();
    for (int i = tid; i < cnt; i += 256) {
        unsigned pk = binned[base + i];
        int pos = atomicAdd(&loff[pk >> 16], 1);
        csr_src[base + pos] = (int)(pk & 0xFFFFu);
    }
}

__global__ void conv_weights(const float* __restrict__ W1, const float* __restrict__ W2,
                             ushort* __restrict__ W1T, ushort* __restrict__ W2T) {
    int i = blockIdx.x * 256 + threadIdx.x;
    if (i < INDIM * HIDDEN) {
        int k = i / HIDDEN, n = i % HIDDEN;
        W1T[n * INDIM + k] = f2bf(W1[i]);
    }
    if (i < HIDDEN * OUTD) {
        int k = i / OUTD, n = i % OUTD;
        W2T[n * HIDDEN + k] = f2bf(W2[i]);
    }
}

// fallback GEMM (256 threads), scale baked into epilogue (dinv available pre-GEMM here)
template<int BM, int BN, int BK, int WM, int WN, bool AFP32>
__global__ __launch_bounds__(256) void gemm_mfma(const void* __restrict__ Ap,
                                                 const ushort* __restrict__ BT,
                                                 unsigned char* __restrict__ C,
                                                 const float* __restrict__ scale,
                                                 int M, int K) {
    constexpr int N   = BN;
    constexpr int FM  = WM / 16, FN = WN / 16;
    constexpr int NWN = BN / WN;
    constexpr int TH  = (BM / WM) * NWN * 64;
    __shared__ ushort Als[BM * BK];
    __shared__ ushort Bls[BN * BK];
    char* Ab = (char*)Als;
    char* Bb = (char*)Bls;
    int tid  = threadIdx.x;
    int lane = tid & 63, w = tid >> 6;
    int wm = w / NWN, wn = w % NWN;
    int m0 = blockIdx.x * BM;
    f32x4 acc[FM][FN] = {};

    for (int kt = 0; kt < K; kt += BK) {
        #pragma unroll
        for (int c = tid; c < BM * BK / 8; c += TH) {
            int row = c / (BK / 8);
            int kc  = (c % (BK / 8)) * 8;
            int off = ((row * BK + kc) * 2) ^ ((row & 7) << 4);
            u16x8 pk = {0, 0, 0, 0, 0, 0, 0, 0};
            int g = m0 + row;
            if (g < M) {
                if (AFP32) {
                    const float* A = (const float*)Ap;
                    float4 v0 = *(const float4*)(A + (long)g * K + kt + kc);
                    float4 v1 = *(const float4*)(A + (long)g * K + kt + kc + 4);
                    pk[0] = f2bf(v0.x); pk[1] = f2bf(v0.y); pk[2] = f2bf(v0.z); pk[3] = f2bf(v0.w);
                    pk[4] = f2bf(v1.x); pk[5] = f2bf(v1.y); pk[6] = f2bf(v1.z); pk[7] = f2bf(v1.w);
                } else {
                    const ushort* A = (const ushort*)Ap;
                    pk = *(const u16x8*)(A + (long)g * K + kt + kc);
                }
            }
            *(u16x8*)(Ab + off) = pk;
        }
        #pragma unroll
        for (int c = tid; c < BN * BK / 8; c += TH) {
            int nn = c / (BK / 8);
            int kc = (c % (BK / 8)) * 8;
            int off = ((nn * BK + kc) * 2) ^ ((nn & 7) << 4);
            *(u16x8*)(Bb + off) = *(const u16x8*)(BT + (long)nn * K + kt + kc);
        }
        __syncthreads();
        #pragma unroll
        for (int kk = 0; kk < BK / 32; ++kk) {
            int kb = kk * 32 + (lane >> 4) * 8;
            bf16x8 af[FM], bfv[FN];
            #pragma unroll
            for (int i = 0; i < FM; ++i) {
                int row = wm * WM + i * 16 + (lane & 15);
                af[i] = *(const bf16x8*)(Ab + (((row * BK + kb) * 2) ^ ((row & 7) << 4)));
            }
            #pragma unroll
            for (int j = 0; j < FN; ++j) {
                int nn = wn * WN + j * 16 + (lane & 15);
                bfv[j] = *(const bf16x8*)(Bb + (((nn * BK + kb) * 2) ^ ((nn & 7) << 4)));
            }
            #pragma unroll
            for (int i = 0; i < FM; ++i)
                #pragma unroll
                for (int j = 0; j < FN; ++j)
                    acc[i][j] = __builtin_amdgcn_mfma_f32_16x16x32_bf16(af[i], bfv[j], acc[i][j], 0, 0, 0);
        }
        __syncthreads();
    }

    #pragma unroll
    for (int i = 0; i < FM; ++i) {
        #pragma unroll
        for (int q = 0; q < 4; ++q) {
            int row = m0 + wm * WM + i * 16 + (lane >> 4) * 4 + q;
            if (row < M) {
                float s = scale[row];
                #pragma unroll
                for (int j = 0; j < FN; ++j) {
                    int col = wn * WN + j * 16 + (lane & 15);
                    C[(long)row * N + col] = fp8_enc(acc[i][j][q] * s);
                }
            }
        }
    }
}

__global__ void agg1_fb(const unsigned char* __restrict__ g1, const int* __restrict__ row_start,
                        const int* __restrict__ csr_src, const float* __restrict__ dinv,
                        const float* __restrict__ b1, ushort* __restrict__ h1, int n) {
    int node = blockIdx.x;
    if (node >= n) return;
    int lane = threadIdx.x;
    int fo = lane * 2;
    ushort sv = *(const ushort*)&g1[(long)node * HIDDEN + fo];
    f32x2 sd = fp8x2_dec((int)sv);
    float a0 = sd[0], a1 = sd[1];
    int s = row_start[node], e = row_start[node + 1];
    int k = s;
    for (; k + 3 < e; k += 4) {
        int s0 = csr_src[k], s1 = csr_src[k + 1], s2 = csr_src[k + 2], s3 = csr_src[k + 3];
        ushort u0 = *(const ushort*)&g1[(long)s0 * HIDDEN + fo];
        ushort u1 = *(const ushort*)&g1[(long)s1 * HIDDEN + fo];
        ushort u2 = *(const ushort*)&g1[(long)s2 * HIDDEN + fo];
        ushort u3 = *(const ushort*)&g1[(long)s3 * HIDDEN + fo];
        f32x2 d0 = fp8x2_dec((int)u0), d1 = fp8x2_dec((int)u1);
        f32x2 d2 = fp8x2_dec((int)u2), d3 = fp8x2_dec((int)u3);
        a0 += (d0[0] + d1[0]) + (d2[0] + d3[0]);
        a1 += (d0[1] + d1[1]) + (d2[1] + d3[1]);
    }
    for (; k < e; ++k) {
        int s0 = csr_src[k];
        f32x2 d0 = fp8x2_dec((int)*(const ushort*)&g1[(long)s0 * HIDDEN + fo]);
        a0 += d0[0];
        a1 += d0[1];
    }
    float d = dinv[node];
    float2 bb = *(const float2*)&b1[fo];
    ushort2 r;
    r.x = f2bf(fmaxf(d * a0 + bb.x, 0.f));
    r.y = f2bf(fmaxf(d * a1 + bb.y, 0.f));
    *(ushort2*)&h1[(long)node * HIDDEN + fo] = r;
}

__global__ void agg2_fb(const unsigned char* __restrict__ g2, const int* __restrict__ row_start,
                        const int* __restrict__ csr_src, const float* __restrict__ dinv,
                        const float* __restrict__ b2, const float* __restrict__ We,
                        const float* __restrict__ be, const float* __restrict__ Wg,
                        const float* __restrict__ bg, const float* __restrict__ rule_w,
                        float* __restrict__ out, int n) {
    int node = blockIdx.x;
    if (node >= n) return;
    int f = threadIdx.x;
    float acc = fp8x2_dec((int)g2[(long)node * OUTD + f])[0];
    int s = row_start[node], e = row_start[node + 1];
    int k = s;
    for (; k + 3 < e; k += 4) {
        int s0 = csr_src[k], s1 = csr_src[k + 1], s2 = csr_src[k + 2], s3 = csr_src[k + 3];
        float v0 = fp8x2_dec((int)g2[(long)s0 * OUTD + f])[0];
        float v1 = fp8x2_dec((int)g2[(long)s1 * OUTD + f])[0];
        float v2 = fp8x2_dec((int)g2[(long)s2 * OUTD + f])[0];
        float v3 = fp8x2_dec((int)g2[(long)s3 * OUTD + f])[0];
        acc += (v0 + v1) + (v2 + v3);
    }
    for (; k < e; ++k) acc += fp8x2_dec((int)g2[(long)csr_src[k] * OUTD + f])[0];
    float h2 = dinv[node] * acc + b2[f];
    float r0 = wsum(h2 * We[f * 3 + 0]) + be[0];
    float r1 = wsum(h2 * We[f * 3 + 1]) + be[1];
    float r2 = wsum(h2 * We[f * 3 + 2]) + be[2];
    float z = r0 * Wg[0] + r1 * Wg[1] + r2 * Wg[2] + bg[0];
    float gate = 1.f / (1.f + expf(-z));
    float h = h2 + gate * rule_w[0];
    float m = wmax(h);
    float sum = wsum(expf(h - m));
    out[(long)node * OUTD + f] = h - m - logf(sum);
}

// ======================= launcher =======================
extern "C" void kernel_launch(void* const* d_in, const int* in_sizes, int n_in,
                              void* d_out, int out_size, void* d_ws, size_t ws_size,
                              hipStream_t stream) {
    const float* x   = (const float*)d_in[0];
    const int*   ei  = (const int*)d_in[1];
    const float* W1  = (const float*)d_in[3];
    const float* b1  = (const float*)d_in[4];
    const float* W2  = (const float*)d_in[5];
    const float* b2  = (const float*)d_in[6];
    const float* We  = (const float*)d_in[7];
    const float* be  = (const float*)d_in[8];
    const float* Wg  = (const float*)d_in[9];
    const float* bg  = (const float*)d_in[10];
    const float* rw  = (const float*)d_in[11];
    float* out = (float*)d_out;

    int n = out_size / OUTD;        // 50000
    int E = in_sizes[1] / 2;        // 800000
    const int* srcv = ei;
    const int* dstv = ei + E;
    int nbkt = (n + 255) / 256;     // 196

    // ---- carve workspace ----
    char* w = (char*)d_ws;
    size_t off = 0;
    auto carve = [&](size_t bytes) -> void* {
        void* p = w + off;
        off += (bytes + 255) & ~(size_t)255;
        return p;
    };
    int*           bkt_cnt   = (int*)carve(256 * 4);
    int*           bkt_off_  = (int*)carve(256 * 4);
    int*           bkt_cur   = (int*)carve(256 * 4);
    int*           tile_ctr  = (int*)carve(256);
    int*           row_start = (int*)carve((size_t)(n + 1) * 4);
    float*         dinv      = (float*)carve((size_t)n * 4);
    unsigned*      binned    = (unsigned*)carve((size_t)E * 4);
    int*           csr_src   = (int*)carve((size_t)E * 4);
    unsigned char* g1        = (unsigned char*)carve((size_t)n * HIDDEN);
    ushort*        h1        = (ushort*)carve((size_t)n * HIDDEN * 2);
    ushort*        W1T       = (ushort*)carve((size_t)HIDDEN * INDIM * 2);
    ushort*        W2T       = (ushort*)carve((size_t)OUTD * HIDDEN * 2);
    unsigned char* g2        = g1;  // reuse: g1 dead after agg1

    // ---- cooperative mega-kernel path ----
    MegaP p;
    p.x = x; p.srcv = srcv; p.dstv = dstv;
    p.W1 = W1; p.b1 = b1; p.W2 = W2; p.b2 = b2;
    p.We = We; p.be = be; p.Wg = Wg; p.bg = bg; p.rw = rw;
    p.out = out; p.n = n; p.E = E; p.nbkt = nbkt;
    p.bkt_cnt = bkt_cnt; p.bkt_off = bkt_off_; p.bkt_cur = bkt_cur;
    p.row_start = row_start; p.dinv = dinv;
    p.binned = binned; p.csr_src = csr_src; p.tile_ctr = tile_ctr;
    p.g1 = g1; p.h1 = h1; p.W1T = W1T; p.W2T = W2T; p.g2 = g2;

    int mab = 0, ncu = 0, dev = 0;
    hipGetDevice(&dev);
    hipDeviceGetAttribute(&ncu, hipDeviceAttributeMultiprocessorCount, dev);
    hipOccupancyMaxActiveBlocksPerMultiprocessor(&mab, (const void*)mega, 512, 0);
    if (ncu <= 0) ncu = 256;

    hipError_t err = hipErrorUnknown;
    if (mab > 0) {
        int grid = mab * ncu;
        if (grid > 2048) grid = 2048;
        void* args[] = { (void*)&p };
        err = hipLaunchCooperativeKernel((const void*)mega, dim3(grid), dim3(512),
                                         args, 0, stream);
    }
    if (err == hipSuccess) return;

    // ---- fallback: round-7 multi-kernel path ----
    hipMemsetAsync(bkt_cnt, 0, 256 * 4, stream);
    conv_weights<<<(INDIM * HIDDEN + 255) / 256, 256, 0, stream>>>(W1, W2, W1T, W2T);
    bin_count<<<(E + 2047) / 2048, 256, 0, stream>>>(dstv, bkt_cnt, E);
    bkt_scan<<<1, 256, 0, stream>>>(bkt_cnt, bkt_off_, bkt_cur, row_start, n, E, nbkt);
    bin_scatter<<<(E + 8191) / 8192, 256, 0, stream>>>(srcv, dstv, bkt_cur, binned, E);
    bkt_build<<<nbkt, 256, 0, stream>>>(binned, bkt_off_, bkt_cnt, row_start, dinv, csr_src, n);
    gemm_mfma<128, 128, 64, 64, 64, true><<<(n + 127) / 128, 256, 0, stream>>>(
        x, W1T, g1, dinv, n, INDIM);
    agg1_fb<<<n, 64, 0, stream>>>(g1, row_start, csr_src, dinv, b1, h1, n);
    gemm_mfma<128, 64, 64, 64, 32, false><<<(n + 127) / 128, 256, 0, stream>>>(
        h1, W2T, g2, dinv, n, HIDDEN);
    agg2_fb<<<n, 64, 0, stream>>>(g2, row_start, csr_src, dinv, b2, We, be, Wg, bg, rw, out, n);
}

// Round 9
// 147.267 us; speedup vs baseline: 3.1711x; 3.1711x over previous
//
#include <hip/hip_runtime.h>

#define INDIM  256
#define HIDDEN 128
#define OUTD   64
#define CHUNK  8192

typedef short  bf16x8 __attribute__((ext_vector_type(8)));
typedef float  f32x4  __attribute__((ext_vector_type(4)));
typedef float  f32x2  __attribute__((ext_vector_type(2)));
typedef ushort u16x8  __attribute__((ext_vector_type(8)));

__device__ inline ushort f2bf(float f) {
    union { float f; unsigned u; } v; v.f = f;
    unsigned u = v.u;
    unsigned r = (u + 0x7FFFu + ((u >> 16) & 1u)) >> 16;  // RNE
    return (ushort)r;
}
__device__ inline f32x2 fp8x2_dec(int packed) {
    return __builtin_amdgcn_cvt_pk_f32_fp8(packed, false);
}
__device__ inline unsigned char fp8_enc(float v) {
    int pk = __builtin_amdgcn_cvt_pk_fp8_f32(v, v, 0, false);
    return (unsigned char)(pk & 0xFF);
}
__device__ inline float wsum(float v) {
    #pragma unroll
    for (int m = 32; m >= 1; m >>= 1) v += __shfl_xor(v, m);
    return v;
}
__device__ inline float wmax(float v) {
    #pragma unroll
    for (int m = 32; m >= 1; m >>= 1) v = fmaxf(v, __shfl_xor(v, m));
    return v;
}

// ================= K1: per-chunk histograms (non-atomic output) + weight conv ==========
__global__ void k1_hist_conv(const int* __restrict__ dst, int* __restrict__ hist,
                             const float* __restrict__ W1, const float* __restrict__ W2,
                             ushort* __restrict__ W1T, ushort* __restrict__ W2T,
                             int E, int nch) {
    int bid = blockIdx.x, tid = threadIdx.x;
    if (bid < nch) {
        __shared__ int h[256];
        h[tid] = 0;
        __syncthreads();
        int base = bid * CHUNK;
        int cnt = min(CHUNK, E - base);
        for (int i = tid; i < cnt; i += 256) atomicAdd(&h[dst[base + i] >> 8], 1);
        __syncthreads();
        hist[bid * 256 + tid] = h[tid];  // single non-atomic write
    } else {
        int j = bid - nch;
        if (j < 128) {                     // W1: [256][128] -> W1T [128][256]
            int i = j * 256 + tid;
            int k = i / HIDDEN, c = i % HIDDEN;
            W1T[c * INDIM + k] = f2bf(W1[i]);
        } else {                           // W2: [128][64] -> W2T [64][128]
            int i = (j - 128) * 256 + tid;
            if (i < HIDDEN * OUTD) {
                int k = i / OUTD, c = i % OUTD;
                W2T[c * HIDDEN + k] = f2bf(W2[i]);
            }
        }
    }
}

// ================= shared MFMA GEMM body (256 threads, raw fp8 out) ==========
// A: [M][K] (fp32 if AFP32 else bf16), BT: [BN][K] bf16, C: [M][BN] fp8 e4m3 (unscaled)
template<int BM, int BN, int WM, int WN, bool AFP32>
__device__ void gemm_body(char* Ab, char* Bb, long m0, const void* Ap,
                          const ushort* __restrict__ BT, unsigned char* __restrict__ C,
                          int M, int K) {
    constexpr int BK  = 64;
    constexpr int FM  = WM / 16, FN = WN / 16;
    constexpr int NWN = BN / WN;
    constexpr int TH  = (BM / WM) * NWN * 64;
    static_assert(TH == 256, "gemm geometry must use 256 threads");
    int tid  = threadIdx.x;
    int lane = tid & 63, w = tid >> 6;
    int wm = w / NWN, wn = w % NWN;
    f32x4 acc[FM][FN] = {};

    for (int kt = 0; kt < K; kt += BK) {
        #pragma unroll
        for (int c = tid; c < BM * BK / 8; c += TH) {
            int row = c / (BK / 8);
            int kc  = (c % (BK / 8)) * 8;
            int off = ((row * BK + kc) * 2) ^ ((row & 7) << 4);
            u16x8 pk = {0, 0, 0, 0, 0, 0, 0, 0};
            long g = m0 + row;
            if (g < M) {
                if (AFP32) {
                    const float* A = (const float*)Ap;
                    float4 v0 = *(const float4*)(A + g * K + kt + kc);
                    float4 v1 = *(const float4*)(A + g * K + kt + kc + 4);
                    pk[0] = f2bf(v0.x); pk[1] = f2bf(v0.y); pk[2] = f2bf(v0.z); pk[3] = f2bf(v0.w);
                    pk[4] = f2bf(v1.x); pk[5] = f2bf(v1.y); pk[6] = f2bf(v1.z); pk[7] = f2bf(v1.w);
                } else {
                    const ushort* A = (const ushort*)Ap;
                    pk = *(const u16x8*)(A + g * K + kt + kc);
                }
            }
            *(u16x8*)(Ab + off) = pk;
        }
        #pragma unroll
        for (int c = tid; c < BN * BK / 8; c += TH) {
            int nn = c / (BK / 8);
            int kc = (c % (BK / 8)) * 8;
            int off = ((nn * BK + kc) * 2) ^ ((nn & 7) << 4);
            *(u16x8*)(Bb + off) = *(const u16x8*)(BT + (long)nn * K + kt + kc);
        }
        __syncthreads();
        #pragma unroll
        for (int kk = 0; kk < BK / 32; ++kk) {
            int kb = kk * 32 + (lane >> 4) * 8;
            bf16x8 af[FM], bfv[FN];
            #pragma unroll
            for (int i = 0; i < FM; ++i) {
                int row = wm * WM + i * 16 + (lane & 15);
                af[i] = *(const bf16x8*)(Ab + (((row * BK + kb) * 2) ^ ((row & 7) << 4)));
            }
            #pragma unroll
            for (int j = 0; j < FN; ++j) {
                int nn = wn * WN + j * 16 + (lane & 15);
                bfv[j] = *(const bf16x8*)(Bb + (((nn * BK + kb) * 2) ^ ((nn & 7) << 4)));
            }
            #pragma unroll
            for (int i = 0; i < FM; ++i)
                #pragma unroll
                for (int j = 0; j < FN; ++j)
                    acc[i][j] = __builtin_amdgcn_mfma_f32_16x16x32_bf16(af[i], bfv[j], acc[i][j], 0, 0, 0);
        }
        __syncthreads();
    }

    #pragma unroll
    for (int i = 0; i < FM; ++i) {
        #pragma unroll
        for (int q = 0; q < 4; ++q) {
            long row = m0 + wm * WM + i * 16 + (lane >> 4) * 4 + q;
            if (row < M) {
                #pragma unroll
                for (int j = 0; j < FN; ++j) {
                    int col = wn * WN + j * 16 + (lane & 15);
                    C[row * BN + col] = fp8_enc(acc[i][j][q]);
                }
            }
        }
    }
}

// ================= K2: block 0 = bucket/cursor scan ; blocks 1.. = gemm1 tiles ==========
__global__ __launch_bounds__(256) void k2_scan_gemm1(
        const int* __restrict__ hist, int* __restrict__ chunkbase,
        int* __restrict__ bkt_off, int* __restrict__ bkt_cnt, int* __restrict__ row_start,
        const float* __restrict__ x, const ushort* __restrict__ W1T,
        unsigned char* __restrict__ g1, int n, int E, int nch) {
    __shared__ alignas(16) char pool[2 * 128 * 64 * 2];  // 32 KB
    if (blockIdx.x == 0) {
        int* s = (int*)pool;
        int tid = threadIdx.x;
        // per-bucket running prefix over chunks (coalesced column walk)
        int run = 0;
        for (int c = 0; c < nch; ++c) {
            int t = hist[c * 256 + tid];
            chunkbase[c * 256 + tid] = run;
            run += t;
        }
        bkt_cnt[tid] = run;
        int v = run;
        s[tid] = v;
        __syncthreads();
        for (int off = 1; off < 256; off <<= 1) {
            int t = (tid >= off) ? s[tid - off] : 0;
            __syncthreads();
            s[tid] += t;
            __syncthreads();
        }
        bkt_off[tid] = s[tid] - v;  // exclusive
        if (tid == 0) row_start[n] = E;
    } else {
        gemm_body<128, 128, 64, 64, true>(pool, pool + 128 * 64 * 2,
                                          (long)(blockIdx.x - 1) * 128, x, W1T, g1, n, INDIM);
    }
}

// ================= K3: scatter packed edges (LDS cursors only, no global atomics) ======
__global__ void k3_scatter(const int* __restrict__ src, const int* __restrict__ dst,
                           const int* __restrict__ bkt_off, const int* __restrict__ chunkbase,
                           unsigned* __restrict__ binned, int E) {
    __shared__ int lbase[256];
    __shared__ int lcur[256];
    int ch = blockIdx.x, tid = threadIdx.x;
    lbase[tid] = bkt_off[tid] + chunkbase[ch * 256 + tid];
    lcur[tid] = 0;
    __syncthreads();
    int base = ch * CHUNK;
    int cnt = min(CHUNK, E - base);
    for (int i = tid; i < cnt; i += 256) {
        int e = base + i;
        int d = dst[e];
        int b = d >> 8;
        int r = atomicAdd(&lcur[b], 1);
        binned[lbase[b] + r] = ((unsigned)(d & 255) << 16) | (unsigned)src[e];
    }
}

// ================= K4: per-bucket build (row_start, dinv, csr_src) ==========
__global__ void k4_build(const unsigned* __restrict__ binned, const int* __restrict__ bkt_off,
                         const int* __restrict__ bkt_cnt, int* __restrict__ row_start,
                         float* __restrict__ dinv, int* __restrict__ csr_src, int n) {
    __shared__ int ldeg[256];
    __shared__ int loff[256];
    int b = blockIdx.x, tid = threadIdx.x;
    int base = bkt_off[b], cnt = bkt_cnt[b];
    ldeg[tid] = 0;
    __syncthreads();
    for (int i = tid; i < cnt; i += 256) atomicAdd(&ldeg[binned[base + i] >> 16], 1);
    __syncthreads();
    int v = ldeg[tid];
    loff[tid] = v;
    __syncthreads();
    for (int off = 1; off < 256; off <<= 1) {
        int t = (tid >= off) ? loff[tid - off] : 0;
        __syncthreads();
        loff[tid] += t;
        __syncthreads();
    }
    int excl = loff[tid] - v;
    int node = b * 256 + tid;
    if (node < n) {
        row_start[node] = base + excl;
        dinv[node] = rsqrtf((float)(v + 1));
    }
    __syncthreads();
    loff[tid] = excl;  // reuse as cursor
    __syncthreads();
    for (int i = tid; i < cnt; i += 256) {
        unsigned pk = binned[base + i];
        int pos = atomicAdd(&loff[pk >> 16], 1);
        csr_src[base + pos] = (int)(pk & 0xFFFFu);
    }
}

// ================= K5: agg1 (dinv-weighted) + bias + relu -> bf16 h1 ==========
__global__ void k5_agg1(const unsigned char* __restrict__ g1, const int* __restrict__ row_start,
                        const int* __restrict__ csr_src, const float* __restrict__ dinv,
                        const float* __restrict__ b1, ushort* __restrict__ h1, int n) {
    int node = blockIdx.x;
    if (node >= n) return;
    int lane = threadIdx.x;  // 0..63
    int fo = lane * 2;
    float dn = dinv[node];
    f32x2 sd = fp8x2_dec((int)*(const ushort*)&g1[(long)node * HIDDEN + fo]);
    float a0 = dn * sd[0], a1 = dn * sd[1];  // self loop
    int s = row_start[node], e = row_start[node + 1];
    int k = s;
    for (; k + 3 < e; k += 4) {
        int s0 = csr_src[k], s1 = csr_src[k + 1], s2 = csr_src[k + 2], s3 = csr_src[k + 3];
        ushort u0 = *(const ushort*)&g1[(long)s0 * HIDDEN + fo];
        ushort u1 = *(const ushort*)&g1[(long)s1 * HIDDEN + fo];
        ushort u2 = *(const ushort*)&g1[(long)s2 * HIDDEN + fo];
        ushort u3 = *(const ushort*)&g1[(long)s3 * HIDDEN + fo];
        float w0 = dinv[s0], w1 = dinv[s1], w2 = dinv[s2], w3 = dinv[s3];
        f32x2 d0 = fp8x2_dec((int)u0), d1 = fp8x2_dec((int)u1);
        f32x2 d2 = fp8x2_dec((int)u2), d3 = fp8x2_dec((int)u3);
        a0 += w0 * d0[0] + w1 * d1[0] + w2 * d2[0] + w3 * d3[0];
        a1 += w0 * d0[1] + w1 * d1[1] + w2 * d2[1] + w3 * d3[1];
    }
    for (; k < e; ++k) {
        int s0 = csr_src[k];
        f32x2 d0 = fp8x2_dec((int)*(const ushort*)&g1[(long)s0 * HIDDEN + fo]);
        float w0 = dinv[s0];
        a0 += w0 * d0[0];
        a1 += w0 * d0[1];
    }
    float2 bb = *(const float2*)&b1[fo];
    ushort2 r;
    r.x = f2bf(fmaxf(dn * a0 + bb.x, 0.f));
    r.y = f2bf(fmaxf(dn * a1 + bb.y, 0.f));
    *(ushort2*)&h1[(long)node * HIDDEN + fo] = r;
}

// ================= K6: gemm2 (h1 @ W2 -> raw fp8 g2) ==========
__global__ __launch_bounds__(256) void k6_gemm2(const ushort* __restrict__ h1,
                                                const ushort* __restrict__ W2T,
                                                unsigned char* __restrict__ g2, int n) {
    __shared__ alignas(16) char pool[128 * 64 * 2 + 64 * 64 * 2];  // 24 KB
    gemm_body<128, 64, 64, 32, false>(pool, pool + 128 * 64 * 2,
                                      (long)blockIdx.x * 128, h1, W2T, g2, n, HIDDEN);
}

// ================= K7: agg2 (dinv-weighted) + rule/gate + log_softmax ==========
__global__ void k7_agg2(const unsigned char* __restrict__ g2, const int* __restrict__ row_start,
                        const int* __restrict__ csr_src, const float* __restrict__ dinv,
                        const float* __restrict__ b2, const float* __restrict__ We,
                        const float* __restrict__ be, const float* __restrict__ Wg,
                        const float* __restrict__ bg, const float* __restrict__ rule_w,
                        float* __restrict__ out, int n) {
    int node = blockIdx.x;
    if (node >= n) return;
    int f = threadIdx.x;  // 0..63
    float dn = dinv[node];
    float acc = dn * fp8x2_dec((int)g2[(long)node * OUTD + f])[0];  // self loop
    int s = row_start[node], e = row_start[node + 1];
    int k = s;
    for (; k + 3 < e; k += 4) {
        int s0 = csr_src[k], s1 = csr_src[k + 1], s2 = csr_src[k + 2], s3 = csr_src[k + 3];
        float v0 = fp8x2_dec((int)g2[(long)s0 * OUTD + f])[0];
        float v1 = fp8x2_dec((int)g2[(long)s1 * OUTD + f])[0];
        float v2 = fp8x2_dec((int)g2[(long)s2 * OUTD + f])[0];
        float v3 = fp8x2_dec((int)g2[(long)s3 * OUTD + f])[0];
        acc += dinv[s0] * v0 + dinv[s1] * v1 + dinv[s2] * v2 + dinv[s3] * v3;
    }
    for (; k < e; ++k) {
        int s0 = csr_src[k];
        acc += dinv[s0] * fp8x2_dec((int)g2[(long)s0 * OUTD + f])[0];
    }
    float h2 = dn * acc + b2[f];
    float r0 = wsum(h2 * We[f * 3 + 0]) + be[0];
    float r1 = wsum(h2 * We[f * 3 + 1]) + be[1];
    float r2 = wsum(h2 * We[f * 3 + 2]) + be[2];
    float z = r0 * Wg[0] + r1 * Wg[1] + r2 * Wg[2] + bg[0];
    float gate = 1.f / (1.f + expf(-z));
    float h = h2 + gate * rule_w[0];
    float m = wmax(h);
    float sum = wsum(expf(h - m));
    out[(long)node * OUTD + f] = h - m - logf(sum);
}

// ======================= launcher (7 dispatches) =======================
extern "C" void kernel_launch(void* const* d_in, const int* in_sizes, int n_in,
                              void* d_out, int out_size, void* d_ws, size_t ws_size,
                              hipStream_t stream) {
    const float* x   = (const float*)d_in[0];
    const int*   ei  = (const int*)d_in[1];
    const float* W1  = (const float*)d_in[3];
    const float* b1  = (const float*)d_in[4];
    const float* W2  = (const float*)d_in[5];
    const float* b2  = (const float*)d_in[6];
    const float* We  = (const float*)d_in[7];
    const float* be  = (const float*)d_in[8];
    const float* Wg  = (const float*)d_in[9];
    const float* bg  = (const float*)d_in[10];
    const float* rw  = (const float*)d_in[11];
    float* out = (float*)d_out;

    int n = out_size / OUTD;        // 50000
    int E = in_sizes[1] / 2;        // 800000
    const int* srcv = ei;
    const int* dstv = ei + E;
    int nch = (E + CHUNK - 1) / CHUNK;  // 98

    // ---- carve workspace ----
    char* w = (char*)d_ws;
    size_t off = 0;
    auto carve = [&](size_t bytes) -> void* {
        void* p = w + off;
        off += (bytes + 255) & ~(size_t)255;
        return p;
    };
    int*           hist      = (int*)carve((size_t)nch * 256 * 4);
    int*           chunkbase = (int*)carve((size_t)nch * 256 * 4);
    int*           bkt_off_  = (int*)carve(256 * 4);
    int*           bkt_cnt   = (int*)carve(256 * 4);
    int*           row_start = (int*)carve((size_t)(n + 1) * 4);
    float*         dinv      = (float*)carve((size_t)n * 4);
    unsigned*      binned    = (unsigned*)carve((size_t)E * 4);
    int*           csr_src   = (int*)carve((size_t)E * 4);
    unsigned char* g1        = (unsigned char*)carve((size_t)n * HIDDEN);
    ushort*        h1        = (ushort*)carve((size_t)n * HIDDEN * 2);
    ushort*        W1T       = (ushort*)carve((size_t)HIDDEN * INDIM * 2);
    ushort*        W2T       = (ushort*)carve((size_t)OUTD * HIDDEN * 2);
    unsigned char* g2        = g1;  // reuse: g1 dead after agg1

    // K1: chunk histograms + weight conversion (98 hist blocks + 160 conv blocks)
    k1_hist_conv<<<nch + 160, 256, 0, stream>>>(dstv, hist, W1, W2, W1T, W2T, E, nch);
    // K2: block 0 scans buckets/cursors; blocks 1..391 compute gemm1 tiles
    k2_scan_gemm1<<<1 + (n + 127) / 128, 256, 0, stream>>>(
        hist, chunkbase, bkt_off_, bkt_cnt, row_start, x, W1T, g1, n, E, nch);
    // K3: scatter packed edges into bucket regions (no global atomics)
    k3_scatter<<<nch, 256, 0, stream>>>(srcv, dstv, bkt_off_, chunkbase, binned, E);
    // K4: per-bucket build -> row_start, dinv, csr_src
    k4_build<<<(n + 255) / 256, 256, 0, stream>>>(binned, bkt_off_, bkt_cnt,
                                                  row_start, dinv, csr_src, n);
    // K5: agg1 + bias + relu -> bf16 h1
    k5_agg1<<<n, 64, 0, stream>>>(g1, row_start, csr_src, dinv, b1, h1, n);
    // K6: gemm2 -> raw fp8 g2
    k6_gemm2<<<(n + 127) / 128, 256, 0, stream>>>(h1, W2T, g2, n);
    // K7: agg2 + rule/gate + log_softmax
    k7_agg2<<<n, 64, 0, stream>>>(g2, row_start, csr_src, dinv, b2, We, be, Wg, bg, rw, out, n);
}